// Round 3
// baseline (248.978 us; speedup 1.0000x reference)
//
#include <hip/hip_runtime.h>

#define BB 32
#define TT 36
#define NN 10000
#define FF 3
#define HH 10
#define RR 20
#define NQ (NN / 4)    // 2500 node-quads per batch
#define TCH 6          // time chunks
#define TSTEPS 6       // steps per chunk

// ws layout (floats):
//   psum : TCH*BB*NQ float4  = 1,920,000 floats
//   pcnt : TCH*BB*NQ float4  = 1,920,000 floats
//   tm   : BB*NN             =   320,000 floats
//   rsum : BB*RR, rcnt: BB*RR, gsum, gcnt, g1

// Stage A: partial NaN-masked sum/count over 6 timesteps per thread.
// grid (10, BB, TCH) x 256 -> 1920 blocks, ~30 waves/CU.
__global__ __launch_bounds__(256) void k_partial(
        const float* __restrict__ seq,
        float4* __restrict__ psum,
        float4* __restrict__ pcnt) {
    const int b = blockIdx.y, tch = blockIdx.z;
    const int q = blockIdx.x * blockDim.x + threadIdx.x;
    if (q >= NQ) return;
    const float4* p = (const float4*)seq
        + (size_t)(b * TT + tch * TSTEPS) * (NN * FF / 4) + 3 * q;
    const size_t tstride = NN * FF / 4;  // 7500 float4 per timestep
    float s0 = 0.f, s1 = 0.f, s2 = 0.f, s3 = 0.f;
    float c0 = 0.f, c1 = 0.f, c2 = 0.f, c3 = 0.f;
    #pragma unroll
    for (int t = 0; t < TSTEPS; ++t) {
        float4 a0 = p[0];
        float4 a1 = p[1];
        float4 a2 = p[2];
        p += tstride;
        float v0 = a0.x, v1 = a0.w, v2 = a1.z, v3 = a2.y;
        if (v0 == v0) { s0 += v0; c0 += 1.f; }
        if (v1 == v1) { s1 += v1; c1 += 1.f; }
        if (v2 == v2) { s2 += v2; c2 += 1.f; }
        if (v3 == v3) { s3 += v3; c3 += 1.f; }
    }
    const size_t o = (size_t)(tch * BB + b) * NQ + q;
    psum[o] = make_float4(s0, s1, s2, s3);
    pcnt[o] = make_float4(c0, c1, c2, c3);
}

// Stage B: reduce the TCH partials, compute per-node means, region/global sums.
__global__ __launch_bounds__(256) void k_finish(
        const float4* __restrict__ psum,
        const float4* __restrict__ pcnt,
        const int* __restrict__ cid,
        float* __restrict__ tm,
        float* __restrict__ rsum,
        float* __restrict__ rcnt,
        float* __restrict__ gsum,
        float* __restrict__ gcnt) {
    __shared__ float ls[RR];
    __shared__ float lc[RR];
    const int b = blockIdx.y;
    const int q = blockIdx.x * blockDim.x + threadIdx.x;
    if (threadIdx.x < RR) { ls[threadIdx.x] = 0.f; lc[threadIdx.x] = 0.f; }
    __syncthreads();

    float lsum = 0.f, lcnt = 0.f;
    if (q < NQ) {
        float s0 = 0.f, s1 = 0.f, s2 = 0.f, s3 = 0.f;
        float c0 = 0.f, c1 = 0.f, c2 = 0.f, c3 = 0.f;
        #pragma unroll
        for (int tch = 0; tch < TCH; ++tch) {
            const size_t o = (size_t)(tch * BB + b) * NQ + q;
            float4 ps = psum[o];
            float4 pc = pcnt[o];
            s0 += ps.x; s1 += ps.y; s2 += ps.z; s3 += ps.w;
            c0 += pc.x; c1 += pc.y; c2 += pc.z; c3 += pc.w;
        }
        const float nanf_ = __int_as_float(0x7fc00000);
        float m0 = (c0 > 0.f) ? s0 / c0 : nanf_;
        float m1 = (c1 > 0.f) ? s1 / c1 : nanf_;
        float m2 = (c2 > 0.f) ? s2 / c2 : nanf_;
        float m3 = (c3 > 0.f) ? s3 / c3 : nanf_;
        ((float4*)tm)[(size_t)b * NQ + q] = make_float4(m0, m1, m2, m3);

        const int4 r4 = ((const int4*)cid)[q];
        if (c0 > 0.f) { atomicAdd(&ls[r4.x], m0); atomicAdd(&lc[r4.x], 1.f); lsum += m0; lcnt += 1.f; }
        if (c1 > 0.f) { atomicAdd(&ls[r4.y], m1); atomicAdd(&lc[r4.y], 1.f); lsum += m1; lcnt += 1.f; }
        if (c2 > 0.f) { atomicAdd(&ls[r4.z], m2); atomicAdd(&lc[r4.z], 1.f); lsum += m2; lcnt += 1.f; }
        if (c3 > 0.f) { atomicAdd(&ls[r4.w], m3); atomicAdd(&lc[r4.w], 1.f); lsum += m3; lcnt += 1.f; }
    }

    for (int off = 32; off > 0; off >>= 1) {
        lsum += __shfl_down(lsum, off, 64);
        lcnt += __shfl_down(lcnt, off, 64);
    }
    if ((threadIdx.x & 63) == 0) {
        atomicAdd(gsum, lsum);
        atomicAdd(gcnt, lcnt);
    }

    __syncthreads();
    if (threadIdx.x < RR) {
        atomicAdd(&rsum[b * RR + threadIdx.x], ls[threadIdx.x]);
        atomicAdd(&rcnt[b * RR + threadIdx.x], lc[threadIdx.x]);
    }
}

// single block, 640 threads (B*R = 640)
__global__ void k_regional(const float* __restrict__ rsum,
                           const float* __restrict__ rcnt,
                           const float* __restrict__ gsum,
                           const float* __restrict__ gcnt,
                           float* __restrict__ g1out,
                           float* __restrict__ out_reg) {
    const int tid = threadIdx.x;
    __shared__ float ssum[10];
    __shared__ float scnt[10];
    __shared__ float g2s;

    float val = 0.f;
    int valid = 0;
    if (tid < BB * RR) {
        float c = rcnt[tid];
        if (c > 0.f) { val = rsum[tid] / c; valid = 1; }
    }

    float wsv = valid ? val : 0.f;
    float wcv = (float)valid;
    for (int off = 32; off > 0; off >>= 1) {
        wsv += __shfl_down(wsv, off, 64);
        wcv += __shfl_down(wcv, off, 64);
    }
    const int wave = tid >> 6;
    if ((tid & 63) == 0) { ssum[wave] = wsv; scnt[wave] = wcv; }
    __syncthreads();

    if (tid == 0) {
        float s = 0.f, c = 0.f;
        #pragma unroll
        for (int i = 0; i < 10; ++i) { s += ssum[i]; c += scnt[i]; }
        g2s = s / c;
        g1out[0] = gsum[0] / gcnt[0];
    }
    __syncthreads();

    if (tid < BB * RR) {
        const int b = tid / RR, r = tid % RR;
        const float o = valid ? val : g2s;
        #pragma unroll
        for (int h = 0; h < HH; ++h)
            out_reg[(size_t)(b * HH + h) * RR + r] = o;
    }
}

__global__ __launch_bounds__(256) void k_pred(
        const float* __restrict__ tm,
        const float* __restrict__ g1p,
        float* __restrict__ out) {
    const int b = blockIdx.y;
    const int q = blockIdx.x * blockDim.x + threadIdx.x;
    if (q >= NQ) return;
    const float g1 = g1p[0];
    float4 v = ((const float4*)tm)[(size_t)b * NQ + q];
    if (!(v.x == v.x)) v.x = g1;
    if (!(v.y == v.y)) v.y = g1;
    if (!(v.z == v.z)) v.z = g1;
    if (!(v.w == v.w)) v.w = g1;
    float4* o = (float4*)out + (size_t)b * HH * NQ + q;
    #pragma unroll
    for (int h = 0; h < HH; ++h)
        o[(size_t)h * NQ] = v;
}

extern "C" void kernel_launch(void* const* d_in, const int* in_sizes, int n_in,
                              void* d_out, int out_size, void* d_ws, size_t ws_size,
                              hipStream_t stream) {
    const float* seq = (const float*)d_in[0];
    const int*   cid = (const int*)d_in[1];
    float* out = (float*)d_out;

    float*  ws   = (float*)d_ws;
    float4* psum = (float4*)ws;                       // TCH*BB*NQ float4
    float4* pcnt = psum + (size_t)TCH * BB * NQ;      // TCH*BB*NQ float4
    float*  tm   = (float*)(pcnt + (size_t)TCH * BB * NQ);  // BB*NN floats
    float*  rsum = tm + (size_t)BB * NN;              // BB*RR
    float*  rcnt = rsum + BB * RR;                    // BB*RR
    float*  gsum = rcnt + BB * RR;                    // 1
    float*  gcnt = gsum + 1;                          // 1
    float*  g1   = gcnt + 1;                          // 1

    hipMemsetAsync(rsum, 0, (size_t)(2 * BB * RR + 2) * sizeof(float), stream);

    dim3 blk(256);
    dim3 grdA((NQ + 255) / 256, BB, TCH);   // 10 x 32 x 6 = 1920 blocks
    dim3 grdB((NQ + 255) / 256, BB);        // 10 x 32
    k_partial<<<grdA, blk, 0, stream>>>(seq, psum, pcnt);
    k_finish<<<grdB, blk, 0, stream>>>(psum, pcnt, cid, tm, rsum, rcnt, gsum, gcnt);
    k_regional<<<1, 640, 0, stream>>>(rsum, rcnt, gsum, gcnt, g1,
                                      out + (size_t)BB * HH * NN);
    k_pred<<<grdB, blk, 0, stream>>>(tm, g1, out);
}